// Round 5
// baseline (635.171 us; speedup 1.0000x reference)
//
#include <hip/hip_runtime.h>

// GeodesicAttentionBlock fused, fp32 in -> fp32 out, MI355X gfx950.
// R11 = R10 resubmit (R4 bench died in the container broker, not the kernel)
// with one safety change: __launch_bounds__(512,6) instead of (512,8) so the
// VGPR cap (~84 vs 64) cannot force scratch spills (R8/R9 lesson: spill
// traffic shows up as +40MB HBM WRITE). Occupancy stays LDS-bound at
// 4 blocks/CU (33.8KB x 4 = 135KB < 160KB) as long as compiler lands <=64
// VGPR (history: 40-52).
//
// Structure: prep builds Wd[w,k] = (Wq_w - Wk_k)L_k, so diff_t = x @ Wd and
// logits come straight off MFMA accumulators (square + 2 shfl). No Kt
// roundtrip, no Qt phase, no Lt, 4 barriers, 2 LDS regions.

typedef __bf16 bf16x8 __attribute__((ext_vector_type(8)));
typedef float  f32x4  __attribute__((ext_vector_type(4)));
typedef int    i32x4  __attribute__((ext_vector_type(4)));
typedef int    i32x2  __attribute__((ext_vector_type(2)));
typedef unsigned short u16;

__device__ __forceinline__ u16 f2bf(float f){
  unsigned int u = __builtin_bit_cast(unsigned int, f);
  u += 0x7FFFu + ((u >> 16) & 1u);          // round-to-nearest-even
  return (u16)(u >> 16);
}
__device__ __forceinline__ unsigned int pk2(float lo, float hi){
  return ((unsigned int)f2bf(hi) << 16) | (unsigned int)f2bf(lo);
}
__device__ __forceinline__ bf16x8 ldfrag_lds(const u16* p){
  return __builtin_bit_cast(bf16x8, *(const i32x4*)p);
}
__device__ __forceinline__ bf16x8 ldfrag_g(const u16* p){
  return __builtin_bit_cast(bf16x8, *(const i32x4*)p);
}

#define LROW 264   // padded bf16 LDS row: 528B stride, 16B-aligned

// ws layout (u16):
//   WdT  @0      : [w=8][256 rows (k*32+f)][256 d]   (1 MB)   row r = col of Wd
//   WvT  @524288 : [256][256]  Wv^T
//   WoutT@589824 : [256][256]  Wout^T
__global__ __launch_bounds__(256) void geo_prep(
    const float* __restrict__ Wq, const float* __restrict__ Wk,
    const float* __restrict__ Wv, const float* __restrict__ Wout,
    const float* __restrict__ L, u16* __restrict__ ws)
{
  const int b = blockIdx.x, t = threadIdx.x;
  if (b < 64){
    // ---- Wd block: pair (w, k).
    // WdT[w][k*32+f][d] = sum_d' (Wq[d][w*32+d'] - Wk[d][k*32+d']) L[k][d'][f]
    const int w = b >> 3, k = b & 7;
    __shared__ float Lsh[32][33];
    #pragma unroll
    for (int i = 0; i < 4; ++i){
      const int idx = t*4 + i;               // d'*32 + f
      Lsh[idx >> 5][idx & 31] = L[k*1024 + idx];
    }
    __syncthreads();
    // thread t owns input-dim d = t
    float diffv[32];
    #pragma unroll
    for (int j4 = 0; j4 < 8; ++j4){
      f32x4 qv = *(const f32x4*)(Wq + (size_t)t*256 + w*32 + j4*4);
      f32x4 kv = *(const f32x4*)(Wk + (size_t)t*256 + k*32 + j4*4);
      #pragma unroll
      for (int p = 0; p < 4; ++p) diffv[j4*4 + p] = qv[p] - kv[p];
    }
    u16* dst = ws + (size_t)w*65536 + (size_t)(k*32)*256 + t;
    #pragma unroll 4
    for (int f = 0; f < 32; ++f){
      float s = 0.f;
      #pragma unroll
      for (int j = 0; j < 32; ++j) s = fmaf(diffv[j], Lsh[j][f], s);
      dst[(size_t)f*256] = f2bf(s);
    }
  } else {
    // ---- transpose blocks: Wv (16 tiles), Wout (16 tiles), 64x64 each
    const int bb = b - 64;
    const int mm = bb >> 4;                  // 0=Wv 1=Wout
    const float* src = mm ? Wout : Wv;
    u16* dstbase = ws + 524288 + mm*65536;
    const int tile = bb & 15;
    const int tr = tile >> 2, tc = tile & 3;
    __shared__ float tlf[64][68];
    {
      const int row = t >> 2, cs = (t & 3)*16;
      #pragma unroll
      for (int j = 0; j < 4; ++j){
        f32x4 v = *(const f32x4*)(src + (size_t)(tr*64 + row)*256 + tc*64 + cs + j*4);
        #pragma unroll
        for (int p = 0; p < 4; ++p) tlf[row][cs + j*4 + p] = v[p];
      }
    }
    __syncthreads();
    {
      const int n = t >> 2, cs = (t & 3)*16;
      float us[16];
      #pragma unroll
      for (int j = 0; j < 16; ++j) us[j] = tlf[cs + j][n];
      #pragma unroll
      for (int h = 0; h < 2; ++h){
        i32x4 o;
        #pragma unroll
        for (int p = 0; p < 4; ++p)
          o[p] = (int)pk2(us[h*8 + 2*p], us[h*8 + 2*p + 1]);
        *(i32x4*)(dstbase + (size_t)(tc*64 + n)*256 + tr*64 + cs + h*8) = o;
      }
    }
  }
}

// LDS regions (33792 B -> 4 blocks/CU):
//   R0 @0     : xs bf16[32][264] -> ao bf16[32][264] after bV (wave-own cols)
//   R1 @16896 : Vs bf16[32][264] -> hs bf16[32][256] after b_ao
__global__ __launch_bounds__(512, 6) void geo_fused(
    const float* __restrict__ x,     const u16* __restrict__ WdT,
    const u16* __restrict__ WvT,     const u16* __restrict__ WoutT,
    const float* __restrict__ b_out, const float* __restrict__ gamma,
    const float* __restrict__ beta,  float* __restrict__ out)
{
  __shared__ __align__(16) char pool[33792];
  u16* xsU = (u16*)(pool);             // [32][264] staging (dead after bV)
  u16* aoU = (u16*)(pool);             // [32][264] attn-out (overlays xs)
  u16* VsU = (u16*)(pool + 16896);     // [32][264] V
  u16* hsU = (u16*)(pool + 16896);     // [32][256] h' (overlays Vs)

  const int t    = threadIdx.x;
  const int lane = t & 63;
  const int w    = t >> 6;             // wave 0..7 == q-head
  const int l15  = lane & 15;
  const int quad = lane >> 4;
  const long rowbase = (long)blockIdx.x * 32;

  // ---- stage x: 32 rows fp32 -> bf16 LDS ----
  {
    const int r  = t >> 4;
    const int c0 = (t & 15) * 16;
    const float* src = x + (rowbase + r)*256 + c0;
    unsigned int wds[8];
    #pragma unroll
    for (int j = 0; j < 4; ++j){
      f32x4 v = *(const f32x4*)(src + j*4);
      wds[j*2    ] = pk2(v[0], v[1]);
      wds[j*2 + 1] = pk2(v[2], v[3]);
    }
    #pragma unroll
    for (int h = 0; h < 2; ++h){
      i32x4 o;
      #pragma unroll
      for (int p = 0; p < 4; ++p) o[p] = (int)wds[h*4 + p];
      *(i32x4*)&xsU[r*LROW + c0 + h*8] = o;
    }
  }
  __syncthreads();   // b0

  // ---- V GEMM (R7 orientation): A=xs rows, B=WvT rows; scalar C-stores ----
  {
    f32x4 acc[2][2];
    #pragma unroll
    for (int mt = 0; mt < 2; ++mt)
      #pragma unroll
      for (int nt = 0; nt < 2; ++nt) acc[mt][nt] = f32x4{0.f,0.f,0.f,0.f};
    #pragma unroll
    for (int kk = 0; kk < 8; ++kk){
      const int c0 = kk*32 + quad*8;
      bf16x8 a[2], bb[2];
      #pragma unroll
      for (int mt = 0; mt < 2; ++mt) a[mt] = ldfrag_lds(&xsU[(mt*16 + l15)*LROW + c0]);
      #pragma unroll
      for (int nt = 0; nt < 2; ++nt)
        bb[nt] = ldfrag_g(WvT + (size_t)(w*32 + nt*16 + l15)*256 + c0);
      #pragma unroll
      for (int mt = 0; mt < 2; ++mt)
        #pragma unroll
        for (int nt = 0; nt < 2; ++nt)
          acc[mt][nt] = __builtin_amdgcn_mfma_f32_16x16x32_bf16(a[mt], bb[nt], acc[mt][nt], 0, 0, 0);
    }
    #pragma unroll
    for (int mt = 0; mt < 2; ++mt)
      #pragma unroll
      for (int nt = 0; nt < 2; ++nt){
        const int col = w*32 + nt*16 + l15;
        #pragma unroll
        for (int reg = 0; reg < 4; ++reg)
          VsU[(mt*16 + quad*4 + reg)*LROW + col] = f2bf(acc[mt][nt][reg]);
      }
  }

  // ---- diff GEMM: diff_t[r, w, k, f] = x_r @ Wd[w,k]; logits in registers ----
  // D[m=f][n=row]: lane holds f = ct*16 + quad*4 + reg, row = nt*16 + l15.
  // sq = sum_f diff^2 -> in-lane 8 squares + shfl x16 + x32.
  float lg[2][8];
  {
    const u16* Wd_w = WdT + (size_t)w*65536;
    #pragma unroll
    for (int k = 0; k < 8; ++k){
      const u16* Ab = Wd_w + (size_t)(k*32)*256;
      f32x4 acc[2][2];   // [ct][nt]
      #pragma unroll
      for (int ct = 0; ct < 2; ++ct)
        #pragma unroll
        for (int nt = 0; nt < 2; ++nt) acc[ct][nt] = f32x4{0.f,0.f,0.f,0.f};
      #pragma unroll
      for (int kk = 0; kk < 8; ++kk){
        const int c0 = kk*32 + quad*8;
        bf16x8 aW[2], bX[2];
        #pragma unroll
        for (int ct = 0; ct < 2; ++ct)
          aW[ct] = ldfrag_g(Ab + (size_t)(ct*16 + l15)*256 + c0);
        #pragma unroll
        for (int nt = 0; nt < 2; ++nt)
          bX[nt] = ldfrag_lds(&xsU[(nt*16 + l15)*LROW + c0]);
        #pragma unroll
        for (int ct = 0; ct < 2; ++ct)
          #pragma unroll
          for (int nt = 0; nt < 2; ++nt)
            acc[ct][nt] = __builtin_amdgcn_mfma_f32_16x16x32_bf16(aW[ct], bX[nt], acc[ct][nt], 0, 0, 0);
      }
      #pragma unroll
      for (int nt = 0; nt < 2; ++nt){
        float s = 0.f;
        #pragma unroll
        for (int ct = 0; ct < 2; ++ct)
          #pragma unroll
          for (int reg = 0; reg < 4; ++reg)
            s = fmaf(acc[ct][nt][reg], acc[ct][nt][reg], s);
        s += __shfl_xor(s, 16);
        s += __shfl_xor(s, 32);            // all lanes: full sum over 32 f
        lg[nt][k] = s * -0.17677669529663687f;   // -1/sqrt(32)
      }
    }
  }
  __syncthreads();   // bV: V complete everywhere; xs dead everywhere

  // ---- softmax + attn @ V -> ao (xs region, wave-own cols) ----
  {
    #pragma unroll
    for (int nt = 0; nt < 2; ++nt){
      const int r = nt*16 + l15;
      float mx = lg[nt][0];
      #pragma unroll
      for (int k = 1; k < 8; ++k) mx = fmaxf(mx, lg[nt][k]);
      float e[8], sum = 0.f;
      #pragma unroll
      for (int k = 0; k < 8; ++k){ e[k] = __expf(lg[nt][k] - mx); sum += e[k]; }
      const float inv = 1.0f / sum;
      float o[8] = {0.f,0.f,0.f,0.f,0.f,0.f,0.f,0.f};
      #pragma unroll
      for (int k = 0; k < 8; ++k){
        i32x4 v = *(const i32x4*)&VsU[r*LROW + k*32 + quad*8];
        const float a = e[k] * inv;
        #pragma unroll
        for (int p = 0; p < 4; ++p){
          unsigned int u = (unsigned int)v[p];
          o[2*p    ] = fmaf(a, __builtin_bit_cast(float, u << 16),         o[2*p    ]);
          o[2*p + 1] = fmaf(a, __builtin_bit_cast(float, u & 0xFFFF0000u), o[2*p + 1]);
        }
      }
      i32x4 pkv;
      #pragma unroll
      for (int p = 0; p < 4; ++p) pkv[p] = (int)pk2(o[2*p], o[2*p + 1]);
      *(i32x4*)&aoU[r*LROW + w*32 + quad*8] = pkv;
    }
  }
  __syncthreads();   // b_ao: ao complete; Vs dead

  // ---- Wout GEMM (R7 orientation): h' = ao @ Wout + b_out -> hs ----
  {
    f32x4 acc[2][2];
    #pragma unroll
    for (int mt = 0; mt < 2; ++mt)
      #pragma unroll
      for (int nt = 0; nt < 2; ++nt) acc[mt][nt] = f32x4{0.f,0.f,0.f,0.f};
    #pragma unroll
    for (int kk = 0; kk < 8; ++kk){
      const int c0 = kk*32 + quad*8;
      bf16x8 a[2], bb[2];
      #pragma unroll
      for (int mt = 0; mt < 2; ++mt) a[mt] = ldfrag_lds(&aoU[(mt*16 + l15)*LROW + c0]);
      #pragma unroll
      for (int nt = 0; nt < 2; ++nt)
        bb[nt] = ldfrag_g(WoutT + (size_t)(w*32 + nt*16 + l15)*256 + c0);
      #pragma unroll
      for (int mt = 0; mt < 2; ++mt)
        #pragma unroll
        for (int nt = 0; nt < 2; ++nt)
          acc[mt][nt] = __builtin_amdgcn_mfma_f32_16x16x32_bf16(a[mt], bb[nt], acc[mt][nt], 0, 0, 0);
    }
    #pragma unroll
    for (int nt = 0; nt < 2; ++nt){
      const int col = w*32 + nt*16 + l15;
      const float bo = b_out[col];
      #pragma unroll
      for (int mt = 0; mt < 2; ++mt)
        #pragma unroll
        for (int reg = 0; reg < 4; ++reg)
          hsU[(mt*16 + quad*4 + reg)*256 + col] = f2bf(acc[mt][nt][reg] + bo);
    }
  }
  __syncthreads();   // b_hs

  // ---- LayerNorm (R7 coalesced mapping): h = hs + x, fp32 store ----
  {
    #pragma unroll
    for (int rr = 0; rr < 4; ++rr){
      const int r = w*4 + rr;
      const int c = lane*4;
      i32x2 h2 = *(const i32x2*)&hsU[r*256 + c];
      f32x4 xv = *(const f32x4*)(x + (rowbase + r)*256 + c);
      unsigned int u0 = (unsigned int)h2[0], u1 = (unsigned int)h2[1];
      f32x4 hv;
      hv[0] = __builtin_bit_cast(float, u0 << 16)         + xv[0];
      hv[1] = __builtin_bit_cast(float, u0 & 0xFFFF0000u) + xv[1];
      hv[2] = __builtin_bit_cast(float, u1 << 16)         + xv[2];
      hv[3] = __builtin_bit_cast(float, u1 & 0xFFFF0000u) + xv[3];
      float s  = hv[0] + hv[1] + hv[2] + hv[3];
      float s2 = hv[0]*hv[0] + hv[1]*hv[1] + hv[2]*hv[2] + hv[3]*hv[3];
      #pragma unroll
      for (int off = 1; off < 64; off <<= 1){
        s  += __shfl_xor(s,  off);
        s2 += __shfl_xor(s2, off);
      }
      const float mu  = s  * (1.0f/256.0f);
      const float var = s2 * (1.0f/256.0f) - mu*mu;
      const float rs  = rsqrtf(var + 1e-5f);
      f32x4 gv = *(const f32x4*)(gamma + c);
      f32x4 bv = *(const f32x4*)(beta  + c);
      f32x4 y;
      y[0] = (hv[0] - mu)*rs*gv[0] + bv[0];
      y[1] = (hv[1] - mu)*rs*gv[1] + bv[1];
      y[2] = (hv[2] - mu)*rs*gv[2] + bv[2];
      y[3] = (hv[3] - mu)*rs*gv[3] + bv[3];
      *(f32x4*)(out + (rowbase + r)*256 + c) = y;
    }
  }
}

extern "C" void kernel_launch(void* const* d_in, const int* in_sizes, int n_in,
                              void* d_out, int out_size, void* d_ws, size_t ws_size,
                              hipStream_t stream)
{
  const float* x     = (const float*)d_in[0];
  const float* Wq    = (const float*)d_in[1];
  const float* Wk    = (const float*)d_in[2];
  const float* Wv    = (const float*)d_in[3];
  const float* Wout  = (const float*)d_in[4];
  const float* b_out = (const float*)d_in[5];
  const float* L     = (const float*)d_in[6];
  const float* gamma = (const float*)d_in[7];
  const float* beta  = (const float*)d_in[8];
  u16* ws = (u16*)d_ws;

  geo_prep<<<96, 256, 0, stream>>>(Wq, Wk, Wv, Wout, L, ws);
  geo_fused<<<2048, 512, 0, stream>>>(x, ws, ws + 524288, ws + 589824,
                                      b_out, gamma, beta, (float*)d_out);
}

// Round 6
// 261.022 us; speedup vs baseline: 2.4334x; 2.4334x over previous
//
#include <hip/hip_runtime.h>

// GeodesicAttentionBlock fused, fp32 in -> fp32 out, MI355X gfx950.
// R12 = R7 (171us anchor, proven counters) + three surgical edits:
//  (1) native (__bf16) casts for all f32->bf16 (compiler emits
//      v_cvt_pk_bf16_f32; manual round-bit f2bf was ~5 VALU ops each,
//      VALU was ~3k instr/wave from counters),
//  (2) barrier b3 removed (Qt reads Qs only at wave-own cols into regs
//      before AV overwrites those cols - logically proven, R8/R9-validated),
//  (3) LN x-tail prefetch issued before b4 so latency hides under Wout.
// R10/R11 lesson (FETCH 924MB): weight footprint must stay L2-resident;
// R7's 0.53MB weight set + WkL fold is the right structure.

typedef __bf16 bf16x8 __attribute__((ext_vector_type(8)));
typedef __bf16 bf16x2 __attribute__((ext_vector_type(2)));
typedef float  f32x4  __attribute__((ext_vector_type(4)));
typedef int    i32x4  __attribute__((ext_vector_type(4)));
typedef int    i32x2  __attribute__((ext_vector_type(2)));
typedef unsigned short u16;

__device__ __forceinline__ u16 f2bf(float f){
  __bf16 b = (__bf16)f;                     // RNE, single v_cvt
  return __builtin_bit_cast(u16, b);
}
__device__ __forceinline__ unsigned int pk2(float lo, float hi){
  bf16x2 v; v[0] = (__bf16)lo; v[1] = (__bf16)hi;   // fuses to v_cvt_pk_bf16_f32
  return __builtin_bit_cast(unsigned int, v);
}
__device__ __forceinline__ bf16x8 ldfrag_lds(const u16* p){
  return __builtin_bit_cast(bf16x8, *(const i32x4*)p);
}
__device__ __forceinline__ bf16x8 ldfrag_g(const u16* p){
  return __builtin_bit_cast(bf16x8, *(const i32x4*)p);
}

#define LROW 264   // padded bf16 LDS row: 528B stride, 16B-aligned

// Kts byte offset, swizzled: [k][r][f] u16, f base fb (multiple of 4).
__device__ __forceinline__ int kts_off(int k, int r, int fb){
  return (k*2048 + r*64 + fb*2) ^ ((r & 7) << 4);
}

// ws layout (u16): WqkvT [768][256] @0 ; WoutT [256][256] @196608 ; Lt [8][32][32] @262144
// WqkvT rows: 0-255 = Wq^T, 256-511 = (Wk·L)^T per head, 512-767 = Wv^T.
// Lt[k][f][d] = L[k][d][f].
__global__ __launch_bounds__(256) void geo_prep(
    const float* __restrict__ Wq, const float* __restrict__ Wk,
    const float* __restrict__ Wv, const float* __restrict__ Wout,
    const float* __restrict__ L, u16* __restrict__ ws)
{
  const int b = blockIdx.x, t = threadIdx.x;
  if (b < 64){
    const int m = b >> 4;                    // 0=Wq 1=Wk(->WkL) 2=Wv 3=Wout
    const float* src = (m == 0) ? Wq : (m == 1) ? Wk : (m == 2) ? Wv : Wout;
    u16* dstbase = (m < 3) ? (ws + m*65536) : (ws + 196608);
    const int tile = b & 15;
    const int tr = tile >> 2, tc = tile & 3;
    __shared__ float tlf[64][68];
    {
      const int row = t >> 2, cs = (t & 3)*16;
      #pragma unroll
      for (int j = 0; j < 4; ++j){
        f32x4 v = *(const f32x4*)(src + (size_t)(tr*64 + row)*256 + tc*64 + cs + j*4);
        #pragma unroll
        for (int p = 0; p < 4; ++p) tlf[row][cs + j*4 + p] = v[p];
      }
    }
    __syncthreads();
    {
      const int n = t >> 2, cs = (t & 3)*16;
      float us[16];
      if (m == 1){
        // WkL^T: out[o=kg*32+f][c] = sum_d Wk[c][kg*32+d] * L[kg][d][f]
        const int hh = n >> 5, f = n & 31;
        const int kg = tc*2 + hh;
        #pragma unroll
        for (int j = 0; j < 16; ++j) us[j] = 0.f;
        #pragma unroll 4
        for (int d = 0; d < 32; ++d){
          const float lv = L[kg*1024 + d*32 + f];
          #pragma unroll
          for (int j = 0; j < 16; ++j)
            us[j] = fmaf(tlf[cs + j][hh*32 + d], lv, us[j]);
        }
      } else {
        #pragma unroll
        for (int j = 0; j < 16; ++j) us[j] = tlf[cs + j][n];
      }
      #pragma unroll
      for (int h = 0; h < 2; ++h){
        i32x4 o;
        #pragma unroll
        for (int p = 0; p < 4; ++p)
          o[p] = (int)pk2(us[h*8 + 2*p], us[h*8 + 2*p + 1]);
        *(i32x4*)(dstbase + (size_t)(tc*64 + n)*256 + tr*64 + cs + h*8) = o;
      }
    }
  } else {
    // Lt: per-head 32x32 transpose of L, fp32 -> bf16
    u16* Lt = ws + 262144;
    const int k = t >> 5, f = t & 31;
    for (int d = 0; d < 32; ++d)
      Lt[k*1024 + f*32 + d] = f2bf(L[k*1024 + d*32 + f]);
  }
}

// LDS regions (50688 B -> 3 blocks/CU):
//   R0 @0     : xs bf16[32][264] -> Kts swz[8][32][32] after b1 -> hs bf16[32][264] after b4
//   R1 @16896 : Qs bf16[32][264] -> ao bf16[32][264] (wave-own cols, no barrier)
//   R2 @33792 : Vs bf16[32][264]
__global__ __launch_bounds__(512, 6) void geo_fused(
    const float* __restrict__ x,     const u16* __restrict__ WqkvT,
    const u16* __restrict__ WoutT,   const u16* __restrict__ Lt,
    const float* __restrict__ b_out, const float* __restrict__ gamma,
    const float* __restrict__ beta,  float* __restrict__ out)
{
  __shared__ __align__(16) char pool[50688];
  u16*  xsU  = (u16*)(pool);           // [32][264] staging (dead after b1)
  char* ktsB = pool;                   // Kts swizzled [8][32][32] (b2..AV)
  u16*  hsU  = (u16*)(pool);           // [32][264] (b4..end)
  u16*  QsU  = (u16*)(pool + 16896);   // [32][264] Q
  u16*  aoU  = (u16*)(pool + 16896);   // [32][264] attn-out (overlays Qs, own cols)
  u16*  VsU  = (u16*)(pool + 33792);   // [32][264] V

  const int t    = threadIdx.x;
  const int lane = t & 63;
  const int w    = t >> 6;             // wave 0..7 == head
  const int l15  = lane & 15;
  const int quad = lane >> 4;
  const long rowbase = (long)blockIdx.x * 32;

  // ---- stage x: 32 rows fp32 -> bf16 LDS ----
  {
    const int r  = t >> 4;
    const int c0 = (t & 15) * 16;
    const float* src = x + (rowbase + r)*256 + c0;
    unsigned int wds[8];
    #pragma unroll
    for (int j = 0; j < 4; ++j){
      f32x4 v = *(const f32x4*)(src + j*4);
      wds[j*2    ] = pk2(v[0], v[1]);
      wds[j*2 + 1] = pk2(v[2], v[3]);
    }
    #pragma unroll
    for (int h = 0; h < 2; ++h){
      i32x4 o;
      #pragma unroll
      for (int p = 0; p < 4; ++p) o[p] = (int)wds[h*4 + p];
      *(i32x4*)&xsU[r*LROW + c0 + h*8] = o;
    }
  }
  __syncthreads();   // b0

  // ---- Q and V GEMMs: wave w computes head-w cols (R7 orientation) ----
  #pragma unroll
  for (int si = 0; si < 2; ++si){
    const int s = si << 1;                       // 0 -> Q, 2 -> V
    const u16* Bbase = WqkvT + (size_t)(s*256 + w*32)*256;
    u16* dst = si ? VsU : QsU;
    f32x4 acc[2][2];
    #pragma unroll
    for (int mt = 0; mt < 2; ++mt)
      #pragma unroll
      for (int nt = 0; nt < 2; ++nt) acc[mt][nt] = f32x4{0.f,0.f,0.f,0.f};
    #pragma unroll
    for (int kk = 0; kk < 8; ++kk){
      const int c0 = kk*32 + quad*8;
      bf16x8 a[2], bb[2];
      #pragma unroll
      for (int mt = 0; mt < 2; ++mt) a[mt] = ldfrag_lds(&xsU[(mt*16 + l15)*LROW + c0]);
      #pragma unroll
      for (int nt = 0; nt < 2; ++nt) bb[nt] = ldfrag_g(Bbase + (size_t)(nt*16 + l15)*256 + c0);
      #pragma unroll
      for (int mt = 0; mt < 2; ++mt)
        #pragma unroll
        for (int nt = 0; nt < 2; ++nt)
          acc[mt][nt] = __builtin_amdgcn_mfma_f32_16x16x32_bf16(a[mt], bb[nt], acc[mt][nt], 0, 0, 0);
    }
    #pragma unroll
    for (int mt = 0; mt < 2; ++mt)
      #pragma unroll
      for (int nt = 0; nt < 2; ++nt){
        const int col = w*32 + nt*16 + l15;
        #pragma unroll
        for (int reg = 0; reg < 4; ++reg)
          dst[(mt*16 + quad*4 + reg)*LROW + col] = f2bf(acc[mt][nt][reg]);
      }
  }

  // ---- K fused: Kt = x @ WkL, acc stays in regs across b1 ----
  f32x4 kacc[2][2];
  {
    #pragma unroll
    for (int mt = 0; mt < 2; ++mt)
      #pragma unroll
      for (int nt = 0; nt < 2; ++nt) kacc[mt][nt] = f32x4{0.f,0.f,0.f,0.f};
    const u16* Abase = WqkvT + (size_t)(256 + w*32)*256;
    #pragma unroll
    for (int kk = 0; kk < 8; ++kk){
      const int c0 = kk*32 + quad*8;
      bf16x8 aW[2], bX[2];
      #pragma unroll
      for (int mt = 0; mt < 2; ++mt) aW[mt] = ldfrag_g(Abase + (size_t)(mt*16 + l15)*256 + c0);
      #pragma unroll
      for (int nt = 0; nt < 2; ++nt) bX[nt] = ldfrag_lds(&xsU[(nt*16 + l15)*LROW + c0]);
      #pragma unroll
      for (int mt = 0; mt < 2; ++mt)
        #pragma unroll
        for (int nt = 0; nt < 2; ++nt)
          kacc[mt][nt] = __builtin_amdgcn_mfma_f32_16x16x32_bf16(aW[mt], bX[nt], kacc[mt][nt], 0, 0, 0);
    }
  }
  __syncthreads();   // b1: xs dead everywhere; Q,V in LDS

  // ---- store Kt into xs region (swizzled) ----
  {
    #pragma unroll
    for (int mt = 0; mt < 2; ++mt)
      #pragma unroll
      for (int nt = 0; nt < 2; ++nt){
        const int r = nt*16 + l15;
        i32x2 o;
        o[0] = (int)pk2(kacc[mt][nt][0], kacc[mt][nt][1]);
        o[1] = (int)pk2(kacc[mt][nt][2], kacc[mt][nt][3]);
        *(i32x2*)(ktsB + kts_off(w, r, mt*16 + quad*4)) = o;
      }
  }
  __syncthreads();   // b2: Kts complete

  // ---- Qt + sq: per k, Qt = L_k^T Q_w; logits to registers ----
  float lg[2][8];
  {
    bf16x8 bQ[2];
    #pragma unroll
    for (int nt = 0; nt < 2; ++nt)
      bQ[nt] = ldfrag_lds(&QsU[(nt*16 + l15)*LROW + w*32 + quad*8]);
    #pragma unroll
    for (int k = 0; k < 8; ++k){
      bf16x8 aL[2];
      #pragma unroll
      for (int mt = 0; mt < 2; ++mt)
        aL[mt] = ldfrag_g(Lt + k*1024 + (mt*16 + l15)*32 + quad*8);
      f32x4 acc[2][2];
      #pragma unroll
      for (int mt = 0; mt < 2; ++mt)
        #pragma unroll
        for (int nt = 0; nt < 2; ++nt)
          acc[mt][nt] = __builtin_amdgcn_mfma_f32_16x16x32_bf16(aL[mt], bQ[nt],
                          f32x4{0.f,0.f,0.f,0.f}, 0, 0, 0);
      #pragma unroll
      for (int nt = 0; nt < 2; ++nt){
        const int r = nt*16 + l15;
        float s = 0.f;
        #pragma unroll
        for (int mt = 0; mt < 2; ++mt){
          i32x2 kt2 = *(const i32x2*)(ktsB + kts_off(k, r, mt*16 + quad*4));
          unsigned int u0 = (unsigned int)kt2[0], u1 = (unsigned int)kt2[1];
          float kv0 = __builtin_bit_cast(float, u0 << 16);
          float kv1 = __builtin_bit_cast(float, u0 & 0xFFFF0000u);
          float kv2 = __builtin_bit_cast(float, u1 << 16);
          float kv3 = __builtin_bit_cast(float, u1 & 0xFFFF0000u);
          float d0 = acc[mt][nt][0] - kv0, d1 = acc[mt][nt][1] - kv1;
          float d2 = acc[mt][nt][2] - kv2, d3 = acc[mt][nt][3] - kv3;
          s = fmaf(d0, d0, s); s = fmaf(d1, d1, s);
          s = fmaf(d2, d2, s); s = fmaf(d3, d3, s);
        }
        s += __shfl_xor(s, 16);
        s += __shfl_xor(s, 32);            // all lanes: full sum over 32 f
        lg[nt][k] = s * -0.17677669529663687f;   // -1/sqrt(32)
      }
    }
  }
  // NO barrier: Qs reads (wave-own cols) are in registers; AV writes only
  // wave-own cols of the same region.

  // ---- softmax + attn @ V -> ao (in Qs region, wave-own cols) ----
  {
    #pragma unroll
    for (int nt = 0; nt < 2; ++nt){
      const int r = nt*16 + l15;
      float mx = lg[nt][0];
      #pragma unroll
      for (int k = 1; k < 8; ++k) mx = fmaxf(mx, lg[nt][k]);
      float e[8], sum = 0.f;
      #pragma unroll
      for (int k = 0; k < 8; ++k){ e[k] = __expf(lg[nt][k] - mx); sum += e[k]; }
      const float inv = 1.0f / sum;
      float o[8] = {0.f,0.f,0.f,0.f,0.f,0.f,0.f,0.f};
      #pragma unroll
      for (int k = 0; k < 8; ++k){
        i32x4 v = *(const i32x4*)&VsU[r*LROW + k*32 + quad*8];
        const float a = e[k] * inv;
        #pragma unroll
        for (int p = 0; p < 4; ++p){
          unsigned int u = (unsigned int)v[p];
          o[2*p    ] = fmaf(a, __builtin_bit_cast(float, u << 16),         o[2*p    ]);
          o[2*p + 1] = fmaf(a, __builtin_bit_cast(float, u & 0xFFFF0000u), o[2*p + 1]);
        }
      }
      i32x4 pkv;
      #pragma unroll
      for (int p = 0; p < 4; ++p) pkv[p] = (int)pk2(o[2*p], o[2*p + 1]);
      *(i32x4*)&aoU[r*LROW + w*32 + quad*8] = pkv;
    }
  }

  // ---- LN x-tail prefetch: issue loads now, consumed after b5 ----
  f32x4 xpre[4];
  #pragma unroll
  for (int rr = 0; rr < 4; ++rr)
    xpre[rr] = *(const f32x4*)(x + (rowbase + w*4 + rr)*256 + lane*4);

  __syncthreads();   // b4: ao complete; Kts dead

  // ---- Wout GEMM: h' = ao @ Wout + b_out -> hs (xs/Kts region) ----
  {
    f32x4 acc[2][2];
    #pragma unroll
    for (int mt = 0; mt < 2; ++mt)
      #pragma unroll
      for (int nt = 0; nt < 2; ++nt) acc[mt][nt] = f32x4{0.f,0.f,0.f,0.f};
    #pragma unroll
    for (int kk = 0; kk < 8; ++kk){
      const int c0 = kk*32 + quad*8;
      bf16x8 a[2], bb[2];
      #pragma unroll
      for (int mt = 0; mt < 2; ++mt) a[mt] = ldfrag_lds(&aoU[(mt*16 + l15)*LROW + c0]);
      #pragma unroll
      for (int nt = 0; nt < 2; ++nt)
        bb[nt] = ldfrag_g(WoutT + (size_t)(w*32 + nt*16 + l15)*256 + c0);
      #pragma unroll
      for (int mt = 0; mt < 2; ++mt)
        #pragma unroll
        for (int nt = 0; nt < 2; ++nt)
          acc[mt][nt] = __builtin_amdgcn_mfma_f32_16x16x32_bf16(a[mt], bb[nt], acc[mt][nt], 0, 0, 0);
    }
    #pragma unroll
    for (int nt = 0; nt < 2; ++nt){
      const int col = w*32 + nt*16 + l15;
      const float bo = b_out[col];
      #pragma unroll
      for (int mt = 0; mt < 2; ++mt)
        #pragma unroll
        for (int reg = 0; reg < 4; ++reg)
          hsU[(mt*16 + quad*4 + reg)*LROW + col] = f2bf(acc[mt][nt][reg] + bo);
    }
  }
  __syncthreads();   // b5

  // ---- LayerNorm (coalesced): h = hs + x(prefetched), fp32 store ----
  {
    #pragma unroll
    for (int rr = 0; rr < 4; ++rr){
      const int r = w*4 + rr;
      const int c = lane*4;
      i32x2 h2 = *(const i32x2*)&hsU[r*LROW + c];
      f32x4 xv = xpre[rr];
      unsigned int u0 = (unsigned int)h2[0], u1 = (unsigned int)h2[1];
      f32x4 hv;
      hv[0] = __builtin_bit_cast(float, u0 << 16)         + xv[0];
      hv[1] = __builtin_bit_cast(float, u0 & 0xFFFF0000u) + xv[1];
      hv[2] = __builtin_bit_cast(float, u1 << 16)         + xv[2];
      hv[3] = __builtin_bit_cast(float, u1 & 0xFFFF0000u) + xv[3];
      float s  = hv[0] + hv[1] + hv[2] + hv[3];
      float s2 = hv[0]*hv[0] + hv[1]*hv[1] + hv[2]*hv[2] + hv[3]*hv[3];
      #pragma unroll
      for (int off = 1; off < 64; off <<= 1){
        s  += __shfl_xor(s,  off);
        s2 += __shfl_xor(s2, off);
      }
      const float mu  = s  * (1.0f/256.0f);
      const float var = s2 * (1.0f/256.0f) - mu*mu;
      const float rs  = rsqrtf(var + 1e-5f);
      f32x4 gv = *(const f32x4*)(gamma + c);
      f32x4 bv = *(const f32x4*)(beta  + c);
      f32x4 y;
      y[0] = (hv[0] - mu)*rs*gv[0] + bv[0];
      y[1] = (hv[1] - mu)*rs*gv[1] + bv[1];
      y[2] = (hv[2] - mu)*rs*gv[2] + bv[2];
      y[3] = (hv[3] - mu)*rs*gv[3] + bv[3];
      *(f32x4*)(out + (rowbase + r)*256 + c) = y;
    }
  }
}

extern "C" void kernel_launch(void* const* d_in, const int* in_sizes, int n_in,
                              void* d_out, int out_size, void* d_ws, size_t ws_size,
                              hipStream_t stream)
{
  const float* x     = (const float*)d_in[0];
  const float* Wq    = (const float*)d_in[1];
  const float* Wk    = (const float*)d_in[2];
  const float* Wv    = (const float*)d_in[3];
  const float* Wout  = (const float*)d_in[4];
  const float* b_out = (const float*)d_in[5];
  const float* L     = (const float*)d_in[6];
  const float* gamma = (const float*)d_in[7];
  const float* beta  = (const float*)d_in[8];
  u16* ws = (u16*)d_ws;

  geo_prep<<<65, 256, 0, stream>>>(Wq, Wk, Wv, Wout, L, ws);
  geo_fused<<<2048, 512, 0, stream>>>(x, ws, ws + 196608, ws + 262144,
                                      b_out, gamma, beta, (float*)d_out);
}